// Round 16
// baseline (36.480 us; speedup 1.0000x reference)
//
#include <hip/hip_runtime.h>

#define NB 32      // batch
#define NM 20      // boxes per image
#define NA 3       // anchors per location
#define NCH 8      // 5 + C channels per anchor
#define N0 49152   // anchors level 0 (128*128*3)
#define N1 12288   // level 1
#define N2 3072    // level 2

// ws layout:
//   partials: L0 32*256*5, L1 32*64*5, L2 32*16*5 = 53760 floats @ ws+0
//   finals:   96*5 {loc, obj_total, cls, num_pos, k}             @ ws+215040
//   keys(u32): 32*(N0+N1+N2) = 2,064,384 (SoA: [lvl][b][a][hw])  @ ws+217088

__device__ __forceinline__ float wredf(float v) {
  #pragma unroll
  for (int o = 32; o; o >>= 1) v += __shfl_down(v, o, 64);
  return v;
}

__device__ __forceinline__ float softplus_neg_abs(float x) {  // log(1+e^-|x|)
  return __logf(1.0f + __expf(-fabsf(x)));
}

// block reduce (1024 thr); result valid on tid 0
__device__ __forceinline__ float blockredf(float v, float* swred, int tid) {
  v = wredf(v);
  if ((tid & 63) == 0) swred[tid >> 6] = v;
  __syncthreads();
  float s = 0.f;
  if (tid == 0) {
    #pragma unroll
    for (int i = 0; i < 16; ++i) s += swred[i];
  }
  __syncthreads();
  return s;
}

// inclusive suffix sum of per-thread value x over 1024 threads (2 barriers)
__device__ __forceinline__ unsigned suffix1024v(unsigned x, unsigned* swq, int tid) {
  #pragma unroll
  for (int o = 1; o < 64; o <<= 1) {
    unsigned t = __shfl_down(x, o, 64);
    if ((tid & 63) + o < 64) x += t;
  }
  unsigned wtot = __shfl(x, 0, 64);
  __syncthreads();                       // protect swq reuse across calls
  if ((tid & 63) == 0) swq[tid >> 6] = wtot;
  __syncthreads();
  unsigned add = 0; const int wv = tid >> 6;
  #pragma unroll
  for (int i = 0; i < 16; ++i) add += (i > wv) ? swq[i] : 0u;
  return x + add;
}

// ---------------- kA: SINGLE-WAVE blocks (64 thr) — no barriers at all -----
// Each block = one wave = 64 locations. Box staging, obj loads, IoU, losses
// run as one un-barriered stream; ~32 independent blocks/CU hide L3 latency.
__global__ __launch_bounds__(64, 8) void kA(
    const float* __restrict__ pr0, const float* __restrict__ pr1,
    const float* __restrict__ pr2,
    const float* __restrict__ boxes, const int* __restrict__ labels,
    unsigned* __restrict__ keys, float* __restrict__ partials)
{
  const int bx = blockIdx.x, b = blockIdx.y, tid = threadIdx.x;
  int blk, wshift, HW, nblk, koff, poff; float stride; const float* pred;
  if (bx < 256)      { blk = bx;       wshift = 7; HW = 16384; nblk = 256; koff = 0;            poff = 0;                          stride = 8.f;  pred = pr0; }
  else if (bx < 320) { blk = bx - 256; wshift = 6; HW = 4096;  nblk = 64;  koff = NB * N0;      poff = NB * 256 * 5;               stride = 16.f; pred = pr1; }
  else               { blk = bx - 320; wshift = 5; HW = 1024;  nblk = 16;  koff = NB * (N0+N1); poff = NB * 256 * 5 + NB * 64 * 5; stride = 32.f; pred = pr2; }

  const int hw = blk * 64 + tid;
  const int W  = 1 << wshift;
  const int w  = hw & (W - 1);
  const int h  = hw >> wshift;
  const float* pb = pred + (size_t)b * (NA * NCH) * HW + hw;

  // issue obj loads FIRST; latency hides under box staging (no barrier below)
  float xo[NA];
  #pragma unroll
  for (int a = 0; a < NA; ++a) xo[a] = pb[(a * NCH + 4) * HW];

  // block's vertical anchor extent (largest anchor half-size = 2*stride)
  const int   h_lo = (blk * 64) >> wshift;
  const int   h_hi = (blk * 64 + 63) >> wshift;
  const float ymin = ((float)h_lo + 0.5f) * stride - 2.f * stride;
  const float ymax = ((float)h_hi + 0.5f) * stride + 2.f * stride;

  // wave-local box staging (compacted; exact no-op cull). Single wave:
  // DS ops are program-ordered, no __syncthreads needed.
  __shared__ float4 sb4[NM + 1];
  __shared__ float  sarea[NM + 1];
  __shared__ int    slab[NM + 1];
  int nv;
  {
    float x1 = 0, y1 = 0, x2 = 0, y2 = 0; int lb = 0; bool v = false;
    if (tid < NM) {
      x1 = boxes[(b * NM + tid) * 4 + 0];
      y1 = boxes[(b * NM + tid) * 4 + 1];
      x2 = boxes[(b * NM + tid) * 4 + 2];
      y2 = boxes[(b * NM + tid) * 4 + 3];
      lb = labels[b * NM + tid];
      v  = (lb > 0) && (y2 > ymin) && (y1 < ymax);
    }
    unsigned long long mask = __ballot(v);
    int pref = __popcll(mask & ((1ull << tid) - 1ull));
    if (v) {
      sb4[pref] = make_float4(x1, y1, x2, y2);
      sarea[pref] = (x2 - x1) * (y2 - y1);
      slab[pref] = lb;
    }
    nv = (int)__popcll(mask);              // wave-uniform
    if (tid == 0) {
      sb4[nv] = make_float4(0.f, 0.f, 0.f, 0.f);  // pad slot for prefetch
      sarea[nv] = 0.f;
    }
  }

  const float cx = ((float)w + 0.5f) * stride;
  const float cy = ((float)h + 0.5f) * stride;

  // anchor corners (exact: cx,cy,hx are integers in fp32)
  float ax1[NA], ay1[NA], ax2[NA], ay2[NA], aar[NA];
  #pragma unroll
  for (int a = 0; a < NA; ++a) {
    const float s  = (2.0f + (float)a) * stride;
    const float hx = 0.5f * s;
    ax1[a] = cx - hx; ax2[a] = cx + hx;
    ay1[a] = cy - hx; ay2[a] = cy + hx;
    aar[a] = s * s;
  }

  // best as (bi, bu) pair; iou_m > iou_best  <=>  inter_m*bu > bi*un_m
  float bi[NA] = {0.f, 0.f, 0.f};
  float bu[NA] = {1.f, 1.f, 1.f};
  int   bm[NA] = {0, 0, 0};

  float4 bb = sb4[0];
  float  ba = sarea[0];
  for (int m = 0; m < nv; ++m) {
    const float4 nb = sb4[m + 1];
    const float  na = sarea[m + 1];
    #pragma unroll
    for (int a = 0; a < NA; ++a) {
      float ix = fminf(ax2[a], bb.z) - fmaxf(ax1[a], bb.x);
      float iy = fminf(ay2[a], bb.w) - fmaxf(ay1[a], bb.y);
      float inter = fmaxf(ix, 0.f) * fmaxf(iy, 0.f);
      float un = (aar[a] + ba) - inter;             // un >= aar >> 1e-9
      bool better = inter * bu[a] > bi[a] * un;     // strict > keeps first argmax
      if (better) { bi[a] = inter; bu[a] = un; bm[a] = m; }
    }
    bb = nb; ba = na;
  }

  float loc_s = 0.f, obj_s = 0.f, cls_s = 0.f;
  float pos_c = 0.f, neg_c = 0.f;

  #pragma unroll
  for (int a = 0; a < NA; ++a) {
    const bool pos = 2.f * bi[a] >= bu[a];          // iou >= 0.5
    const bool neg = bi[a] < 0.3f * bu[a];          // iou < 0.3
    const float x  = xo[a];
    const float sp = softplus_neg_abs(x);

    unsigned key = 0u;  // sentinel: below every mapped neg value
    if (pos) {
      const int m = bm[a];
      pos_c += 1.f;
      obj_s += fmaxf(x, 0.f) - x + sp;              // BCE target 1
      const float4 tb = sb4[m];
      float d0 = fabsf(pb[(a * NCH + 0) * HW] - tb.x);
      float d1 = fabsf(pb[(a * NCH + 1) * HW] - tb.y);
      float d2 = fabsf(pb[(a * NCH + 2) * HW] - tb.z);
      float d3 = fabsf(pb[(a * NCH + 3) * HW] - tb.w);
      float ls = ((d0 < 1.f) ? 0.5f * d0 * d0 : (d0 - 0.5f))
               + ((d1 < 1.f) ? 0.5f * d1 * d1 : (d1 - 0.5f))
               + ((d2 < 1.f) ? 0.5f * d2 * d2 : (d2 - 0.5f))
               + ((d3 < 1.f) ? 0.5f * d3 * d3 : (d3 - 0.5f));
      loc_s += 0.25f * ls;
      float l0 = pb[(a * NCH + 5) * HW];
      float l1 = pb[(a * NCH + 6) * HW];
      float l2 = pb[(a * NCH + 7) * HW];
      float mx  = fmaxf(fmaxf(l0, l1), l2);
      float lse = mx + __logf(__expf(l0 - mx) + __expf(l1 - mx) + __expf(l2 - mx));
      int tgt = slab[m] - 1; tgt = tgt < 0 ? 0 : (tgt > 2 ? 2 : tgt);
      float lt = (tgt == 0) ? l0 : ((tgt == 1) ? l1 : l2);
      cls_s += lse - lt;
    } else if (neg) {
      neg_c += 1.f;
      float bn = fmaxf(x, 0.f) + sp;                // BCE target 0 (>= 0)
      key = __float_as_uint(bn) | 0x80000000u;      // monotone map
    }
    // SoA layout: [a][hw] -> coalesced; kB is order-invariant
    keys[koff + b * (HW * NA) + a * HW + hw] = key;
  }

  // wave-level reduction only; lane 0 stores the block's 5 partials
  loc_s = wredf(loc_s); obj_s = wredf(obj_s); cls_s = wredf(cls_s);
  pos_c = wredf(pos_c); neg_c = wredf(neg_c);
  if (tid == 0) {
    float* slot = partials + poff + (size_t)(b * nblk + blk) * 5;
    slot[0] = loc_s; slot[1] = obj_s; slot[2] = cls_s;
    slot[3] = pos_c; slot[4] = neg_c;
  }
}

// ---------------- kB core: register-resident radix top-k sum (12/10/10) ---
template<int NL4, bool GUARD>
__device__ float kb_core(const unsigned* __restrict__ kp, int n4, unsigned k,
                         unsigned* hist /*4096*/, float* fsum /*1024*/,
                         unsigned* swq, float* swred,
                         unsigned* sh_sel, unsigned* sh_r, int tid)
{
  const uint4* kp4 = (const uint4*)kp;
  uint4 v[NL4];

  for (int i = tid; i < 4096; i += 1024) hist[i] = 0u;
  __syncthreads();

  #pragma unroll
  for (int j = 0; j < NL4; ++j)
    if (!GUARD || tid + j * 1024 < n4) v[j] = kp4[tid + j * 1024];

  // ---- pass 0: 12-bit histogram (bits 31:20)
  #pragma unroll
  for (int j = 0; j < NL4; ++j)
    if (!GUARD || tid + j * 1024 < n4) {
      atomicAdd(&hist[v[j].x >> 20], 1u);
      atomicAdd(&hist[v[j].y >> 20], 1u);
      atomicAdd(&hist[v[j].z >> 20], 1u);
      atomicAdd(&hist[v[j].w >> 20], 1u);
    }
  __syncthreads();

  unsigned c0 = hist[tid*4], c1 = hist[tid*4+1], c2 = hist[tid*4+2], c3 = hist[tid*4+3];
  unsigned st = c0 + c1 + c2 + c3;
  unsigned I = suffix1024v(st, swq, tid);
  unsigned H = I - st;
  if (H < k && k <= I) {          // exactly one thread crosses
    unsigned cum = H;
    if (cum + c3 >= k)      { *sh_sel = tid*4+3; *sh_r = k - cum; }
    else { cum += c3;
      if (cum + c2 >= k)    { *sh_sel = tid*4+2; *sh_r = k - cum; }
      else { cum += c2;
        if (cum + c1 >= k)  { *sh_sel = tid*4+1; *sh_r = k - cum; }
        else { cum += c1;     *sh_sel = tid*4;   *sh_r = k - cum; } } }
  }
  __syncthreads();
  const unsigned pref0 = *sh_sel;
  const unsigned r1    = *sh_r;
  __syncthreads();

  // ---- pass 1: 10-bit hist (bits 19:10) for bucket0; reg-accumulate S above
  hist[tid] = 0u; fsum[tid] = 0.f;
  __syncthreads();
  float s_above = 0.f;
  #pragma unroll
  for (int j = 0; j < NL4; ++j)
    if (!GUARD || tid + j * 1024 < n4) {
      #pragma unroll
      for (int cc = 0; cc < 4; ++cc) {
        unsigned u = (&v[j].x)[cc];
        unsigned d = u >> 20;
        float val = __uint_as_float(u & 0x7fffffffu);
        if (d > pref0) s_above += val;
        else if (d == pref0) {
          unsigned s2 = (u >> 10) & 1023u;
          atomicAdd(&hist[s2], 1u);
          atomicAdd(&fsum[s2], val);
        }
      }
    }
  __syncthreads();
  float S0 = blockredf(s_above, swred, tid);

  unsigned cc1 = hist[tid];
  unsigned I1 = suffix1024v(cc1, swq, tid);
  unsigned H1 = I1 - cc1;
  if (H1 < r1 && r1 <= I1) { *sh_sel = (unsigned)tid; *sh_r = r1 - H1; }
  __syncthreads();
  const unsigned sel1 = *sh_sel;
  const unsigned r2   = *sh_r;
  float S1 = blockredf(tid > (int)sel1 ? fsum[tid] : 0.f, swred, tid);

  // ---- pass 2: final 10 bits (9:0)
  hist[tid] = 0u; fsum[tid] = 0.f;
  __syncthreads();
  const unsigned pref01 = (pref0 << 10) | sel1;
  #pragma unroll
  for (int j = 0; j < NL4; ++j)
    if (!GUARD || tid + j * 1024 < n4) {
      #pragma unroll
      for (int cc = 0; cc < 4; ++cc) {
        unsigned u = (&v[j].x)[cc];
        if ((u >> 10) == pref01) {
          atomicAdd(&hist[u & 1023u], 1u);
          atomicAdd(&fsum[u & 1023u], __uint_as_float(u & 0x7fffffffu));
        }
      }
    }
  __syncthreads();

  unsigned cc2 = hist[tid];
  unsigned I2 = suffix1024v(cc2, swq, tid);
  unsigned H2 = I2 - cc2;
  if (H2 < r2 && r2 <= I2) { *sh_sel = (unsigned)tid; *sh_r = r2 - H2; }
  __syncthreads();
  const unsigned sel2 = *sh_sel;
  const unsigned r3   = *sh_r;
  float S2 = blockredf(tid > (int)sel2 ? fsum[tid] : 0.f, swred, tid);

  const unsigned T = (pref01 << 10) | sel2;    // exact k-th largest key
  const float Tval = __uint_as_float(T & 0x7fffffffu);
  return S0 + S1 + S2 + Tval * (float)r3;      // valid on tid 0
}

__global__ __launch_bounds__(1024) void kB(const unsigned* __restrict__ keys,
                                           const float* __restrict__ partials,
                                           float* __restrict__ finals)
{
  __shared__ unsigned hist[4096];
  __shared__ float    fsum[1024];
  __shared__ unsigned swq[16];
  __shared__ float    swred[16];
  __shared__ float    gp[5];
  __shared__ unsigned sh_sel, sh_r;

  const int bl = blockIdx.x, lvl = bl / NB, b = bl % NB, tid = threadIdx.x;
  const int NLs[3]   = {N0, N1, N2};
  const int BASEs[3] = {0, NB * N0, NB * (N0 + N1)};
  const int NSL[3]   = {256, 64, 16};
  const int POFF[3]  = {0, NB * 256 * 5, NB * 256 * 5 + NB * 64 * 5};

  {
    float v0=0,v1=0,v2=0,v3=0,v4=0;
    if (tid < NSL[lvl]) {
      const float* pp = partials + POFF[lvl] + (size_t)(b * NSL[lvl] + tid) * 5;
      v0=pp[0]; v1=pp[1]; v2=pp[2]; v3=pp[3]; v4=pp[4];
    }
    float s0 = blockredf(v0, swred, tid);
    float s1 = blockredf(v1, swred, tid);
    float s2 = blockredf(v2, swred, tid);
    float s3 = blockredf(v3, swred, tid);
    float s4 = blockredf(v4, swred, tid);
    if (tid==0){gp[0]=s0;gp[1]=s1;gp[2]=s2;gp[3]=s3;gp[4]=s4;}
  }
  __syncthreads();
  const int np = (int)gp[3], nn = (int)gp[4];
  const int k  = (np == 0) ? (nn < 100 ? nn : 100)
                           : (np * 3 < nn ? np * 3 : nn);

  float topk = 0.f;
  if (k > 0) {
    const unsigned* kp = keys + BASEs[lvl] + (size_t)b * NLs[lvl];
    if (lvl == 0)      topk = kb_core<12,false>(kp, 12288, (unsigned)k, hist, fsum, swq, swred, &sh_sel, &sh_r, tid);
    else if (lvl == 1) topk = kb_core<3, false>(kp, 3072,  (unsigned)k, hist, fsum, swq, swred, &sh_sel, &sh_r, tid);
    else               topk = kb_core<1, true >(kp, 768,   (unsigned)k, hist, fsum, swq, swred, &sh_sel, &sh_r, tid);
  }
  if (tid == 0) {
    float* f = finals + (size_t)bl * 5;
    f[0] = gp[0];
    f[1] = gp[1] + topk;
    f[2] = gp[2];
    f[3] = gp[3];
    f[4] = (float)k;
  }
}

__global__ void kC(const float* __restrict__ finals, float* __restrict__ out)
{
  const int tid = threadIdx.x;  // 128 threads
  float loc = 0.f, obj = 0.f, cls = 0.f, pos = 0.f, sel = 0.f;
  if (tid < 96) {
    const float* f = finals + (size_t)tid * 5;
    loc = f[0]; obj = f[1]; cls = f[2]; pos = f[3]; sel = f[4];
  }
  loc = wredf(loc); obj = wredf(obj); cls = wredf(cls);
  pos = wredf(pos); sel = wredf(sel);
  __shared__ float sf[5][2];
  const int wv = tid >> 6;
  if ((tid & 63) == 0) { sf[0][wv] = loc; sf[1][wv] = obj; sf[2][wv] = cls;
                         sf[3][wv] = pos; sf[4][wv] = sel; }
  __syncthreads();
  if (tid == 0) {
    float L  = sf[0][0] + sf[0][1];
    float O  = sf[1][0] + sf[1][1];
    float Cl = sf[2][0] + sf[2][1];
    float P  = sf[3][0] + sf[3][1];
    float S  = sf[4][0] + sf[4][1];
    float norm  = fmaxf(P + S, 1.f);
    float l_loc = 2.0f * L / norm;
    float l_obj = O / norm;
    float l_cls = Cl / fmaxf(P, 1.f);
    out[0] = l_loc + l_obj + l_cls;
    out[1] = l_loc;
    out[2] = l_obj;
    out[3] = l_cls;
  }
}

extern "C" void kernel_launch(void* const* d_in, const int* in_sizes, int n_in,
                              void* d_out, int out_size, void* d_ws, size_t ws_size,
                              hipStream_t stream) {
  const float* p1     = (const float*)d_in[0];
  const float* p2     = (const float*)d_in[1];
  const float* p3     = (const float*)d_in[2];
  // d_in[3..5] = anchors (recomputed analytically in-kernel; exact in fp32)
  const float* boxes  = (const float*)d_in[6];
  const int*   labels = (const int*)d_in[7];
  float* out = (float*)d_out;

  char* ws = (char*)d_ws;
  float*    partials = (float*)ws;             // 53760 floats
  float*    finals   = (float*)(ws + 215040);  // 480 floats
  unsigned* keys     = (unsigned*)(ws + 217088);

  kA<<<dim3(336, NB), 64, 0, stream>>>(p1, p2, p3, boxes, labels, keys, partials);
  kB<<<96, 1024, 0, stream>>>(keys, partials, finals);
  kC<<<1, 128, 0, stream>>>(finals, out);
}

// Round 17
// 35.122 us; speedup vs baseline: 1.0387x; 1.0387x over previous
//
#include <hip/hip_runtime.h>

#define NB 32      // batch
#define NM 20      // boxes per image
#define NA 3       // anchors per location
#define NCH 8      // 5 + C channels per anchor
#define N0 49152   // anchors level 0 (128*128*3)
#define N1 12288   // level 1
#define N2 3072    // level 2

// ws layout:
//   partials: L0 32*64*5, L1 32*16*5, L2 32*4*5 = 13440 floats   @ ws+0
//   finals:   96*5 {loc, obj_total, cls, num_pos, k}             @ ws+53760
//   keys(u32): 32*(N0+N1+N2) = 2,064,384 (SoA: [lvl][b][a][hw])  @ ws+57344

__device__ __forceinline__ float wredf(float v) {
  #pragma unroll
  for (int o = 32; o; o >>= 1) v += __shfl_down(v, o, 64);
  return v;
}

__device__ __forceinline__ float softplus_neg_abs(float x) {  // log(1+e^-|x|)
  return __logf(1.0f + __expf(-fabsf(x)));
}

// block reduce (1024 thr); result valid on tid 0
__device__ __forceinline__ float blockredf(float v, float* swred, int tid) {
  v = wredf(v);
  if ((tid & 63) == 0) swred[tid >> 6] = v;
  __syncthreads();
  float s = 0.f;
  if (tid == 0) {
    #pragma unroll
    for (int i = 0; i < 16; ++i) s += swred[i];
  }
  __syncthreads();
  return s;
}

// inclusive suffix sum of per-thread value x over 1024 threads (2 barriers)
__device__ __forceinline__ unsigned suffix1024v(unsigned x, unsigned* swq, int tid) {
  #pragma unroll
  for (int o = 1; o < 64; o <<= 1) {
    unsigned t = __shfl_down(x, o, 64);
    if ((tid & 63) + o < 64) x += t;
  }
  unsigned wtot = __shfl(x, 0, 64);
  __syncthreads();                       // protect swq reuse across calls
  if ((tid & 63) == 0) swq[tid >> 6] = wtot;
  __syncthreads();
  unsigned add = 0; const int wv = tid >> 6;
  #pragma unroll
  for (int i = 0; i < 16; ++i) add += (i > wv) ? swq[i] : 0u;
  return x + add;
}

// ---------------- kA: per-anchor classification + pos losses + key emit ----
// Best-measured configuration (R11): 256-thr blocks, launch_bounds (256,4),
// y-cull box compaction, branch-free division-free IoU loop via (inter,union)
// pair + cross-multiplication argmax (exact), SoA coalesced key stores.
__global__ __launch_bounds__(256, 4) void kA(
    const float* __restrict__ pr0, const float* __restrict__ pr1,
    const float* __restrict__ pr2,
    const float* __restrict__ boxes, const int* __restrict__ labels,
    unsigned* __restrict__ keys, float* __restrict__ partials)
{
  const int bx = blockIdx.x, b = blockIdx.y, tid = threadIdx.x;
  int blk, wshift, HW, nblk, koff, poff; float stride; const float* pred;
  if (bx < 64)      { blk = bx;      wshift = 7; HW = 16384; nblk = 64; koff = 0;            poff = 0;                         stride = 8.f;  pred = pr0; }
  else if (bx < 80) { blk = bx - 64; wshift = 6; HW = 4096;  nblk = 16; koff = NB * N0;      poff = NB * 64 * 5;               stride = 16.f; pred = pr1; }
  else              { blk = bx - 80; wshift = 5; HW = 1024;  nblk = 4;  koff = NB * (N0+N1); poff = NB * 64 * 5 + NB * 16 * 5; stride = 32.f; pred = pr2; }

  // block's vertical anchor extent (largest anchor half-size = 2*stride)
  const int   nrows = 256 >> wshift;
  const int   h0    = blk * nrows;
  const float ymin  = ((float)h0 + 0.5f) * stride - 2.f * stride;
  const float ymax  = ((float)(h0 + nrows - 1) + 0.5f) * stride + 2.f * stride;

  // compacted boxes: valid label AND vertically overlapping this block's strip
  __shared__ float4 sb4[NM + 1];
  __shared__ float  sarea[NM + 1];
  __shared__ int    slab[NM + 1];
  __shared__ int    s_nv;
  if (tid < 64) {
    float x1 = 0, y1 = 0, x2 = 0, y2 = 0; int lb = 0; bool v = false;
    if (tid < NM) {
      x1 = boxes[(b * NM + tid) * 4 + 0];
      y1 = boxes[(b * NM + tid) * 4 + 1];
      x2 = boxes[(b * NM + tid) * 4 + 2];
      y2 = boxes[(b * NM + tid) * 4 + 3];
      lb = labels[b * NM + tid];
      v  = (lb > 0) && (y2 > ymin) && (y1 < ymax);
    }
    unsigned long long mask = __ballot(v);
    int pref = __popcll(mask & ((1ull << tid) - 1ull));
    if (v) {
      sb4[pref] = make_float4(x1, y1, x2, y2);
      sarea[pref] = (x2 - x1) * (y2 - y1);
      slab[pref] = lb;
    }
    if (tid == 0) {
      int nv = (int)__popcll(mask);
      s_nv = nv;
      sb4[nv] = make_float4(0.f, 0.f, 0.f, 0.f);   // pad slot for prefetch
      sarea[nv] = 0.f;
    }
  }
  __syncthreads();

  const int hw = blk * 256 + tid;
  const int W  = 1 << wshift;
  const int w  = hw & (W - 1);
  const int h  = hw >> wshift;
  const float cx = ((float)w + 0.5f) * stride;
  const float cy = ((float)h + 0.5f) * stride;
  const float* pb = pred + (size_t)b * (NA * NCH) * HW + hw;

  float xo[NA];
  #pragma unroll
  for (int a = 0; a < NA; ++a) xo[a] = pb[(a * NCH + 4) * HW];

  // anchor corners (exact: cx,cy,hx are integers in fp32)
  float ax1[NA], ay1[NA], ax2[NA], ay2[NA], aar[NA];
  #pragma unroll
  for (int a = 0; a < NA; ++a) {
    const float s  = (2.0f + (float)a) * stride;
    const float hx = 0.5f * s;
    ax1[a] = cx - hx; ax2[a] = cx + hx;
    ay1[a] = cy - hx; ay2[a] = cy + hx;
    aar[a] = s * s;
  }

  // best as (bi, bu) pair; iou_m > iou_best  <=>  inter_m*bu > bi*un_m
  float bi[NA] = {0.f, 0.f, 0.f};
  float bu[NA] = {1.f, 1.f, 1.f};
  int   bm[NA] = {0, 0, 0};
  const int nv = s_nv;

  float4 bb = sb4[0];
  float  ba = sarea[0];
  for (int m = 0; m < nv; ++m) {
    const float4 nb = sb4[m + 1];
    const float  na = sarea[m + 1];
    #pragma unroll
    for (int a = 0; a < NA; ++a) {
      float ix = fminf(ax2[a], bb.z) - fmaxf(ax1[a], bb.x);
      float iy = fminf(ay2[a], bb.w) - fmaxf(ay1[a], bb.y);
      float inter = fmaxf(ix, 0.f) * fmaxf(iy, 0.f);
      float un = (aar[a] + ba) - inter;             // un >= aar >> 1e-9
      bool better = inter * bu[a] > bi[a] * un;     // strict > keeps first argmax
      if (better) { bi[a] = inter; bu[a] = un; bm[a] = m; }
    }
    bb = nb; ba = na;
  }

  float loc_s = 0.f, obj_s = 0.f, cls_s = 0.f;
  float pos_c = 0.f, neg_c = 0.f;

  #pragma unroll
  for (int a = 0; a < NA; ++a) {
    const bool pos = 2.f * bi[a] >= bu[a];          // iou >= 0.5
    const bool neg = bi[a] < 0.3f * bu[a];          // iou < 0.3
    const float x  = xo[a];
    const float sp = softplus_neg_abs(x);

    unsigned key = 0u;  // sentinel: below every mapped neg value
    if (pos) {
      const int m = bm[a];
      pos_c += 1.f;
      obj_s += fmaxf(x, 0.f) - x + sp;              // BCE target 1
      const float4 tb = sb4[m];
      float d0 = fabsf(pb[(a * NCH + 0) * HW] - tb.x);
      float d1 = fabsf(pb[(a * NCH + 1) * HW] - tb.y);
      float d2 = fabsf(pb[(a * NCH + 2) * HW] - tb.z);
      float d3 = fabsf(pb[(a * NCH + 3) * HW] - tb.w);
      float ls = ((d0 < 1.f) ? 0.5f * d0 * d0 : (d0 - 0.5f))
               + ((d1 < 1.f) ? 0.5f * d1 * d1 : (d1 - 0.5f))
               + ((d2 < 1.f) ? 0.5f * d2 * d2 : (d2 - 0.5f))
               + ((d3 < 1.f) ? 0.5f * d3 * d3 : (d3 - 0.5f));
      loc_s += 0.25f * ls;
      float l0 = pb[(a * NCH + 5) * HW];
      float l1 = pb[(a * NCH + 6) * HW];
      float l2 = pb[(a * NCH + 7) * HW];
      float mx  = fmaxf(fmaxf(l0, l1), l2);
      float lse = mx + __logf(__expf(l0 - mx) + __expf(l1 - mx) + __expf(l2 - mx));
      int tgt = slab[m] - 1; tgt = tgt < 0 ? 0 : (tgt > 2 ? 2 : tgt);
      float lt = (tgt == 0) ? l0 : ((tgt == 1) ? l1 : l2);
      cls_s += lse - lt;
    } else if (neg) {
      neg_c += 1.f;
      float bn = fmaxf(x, 0.f) + sp;                // BCE target 0 (>= 0)
      key = __float_as_uint(bn) | 0x80000000u;      // monotone map
    }
    // SoA layout: [a][hw] -> coalesced; kB is order-invariant
    keys[koff + b * (HW * NA) + a * HW + hw] = key;
  }

  loc_s = wredf(loc_s); obj_s = wredf(obj_s); cls_s = wredf(cls_s);
  pos_c = wredf(pos_c); neg_c = wredf(neg_c);
  __shared__ float sred[4][5];
  const int wv = tid >> 6;
  if ((tid & 63) == 0) {
    sred[wv][0] = loc_s; sred[wv][1] = obj_s; sred[wv][2] = cls_s;
    sred[wv][3] = pos_c; sred[wv][4] = neg_c;
  }
  __syncthreads();
  if (tid == 0) {
    float* slot = partials + poff + (size_t)(b * nblk + blk) * 5;
    #pragma unroll
    for (int j = 0; j < 5; ++j)
      slot[j] = sred[0][j] + sred[1][j] + sred[2][j] + sred[3][j];
  }
}

// ---------------- kB core: register-resident radix top-k sum (12/10/10) ---
template<int NL4, bool GUARD>
__device__ float kb_core(const unsigned* __restrict__ kp, int n4, unsigned k,
                         unsigned* hist /*4096*/, float* fsum /*1024*/,
                         unsigned* swq, float* swred,
                         unsigned* sh_sel, unsigned* sh_r, int tid)
{
  const uint4* kp4 = (const uint4*)kp;
  uint4 v[NL4];

  for (int i = tid; i < 4096; i += 1024) hist[i] = 0u;
  __syncthreads();

  #pragma unroll
  for (int j = 0; j < NL4; ++j)
    if (!GUARD || tid + j * 1024 < n4) v[j] = kp4[tid + j * 1024];

  // ---- pass 0: 12-bit histogram (bits 31:20)
  #pragma unroll
  for (int j = 0; j < NL4; ++j)
    if (!GUARD || tid + j * 1024 < n4) {
      atomicAdd(&hist[v[j].x >> 20], 1u);
      atomicAdd(&hist[v[j].y >> 20], 1u);
      atomicAdd(&hist[v[j].z >> 20], 1u);
      atomicAdd(&hist[v[j].w >> 20], 1u);
    }
  __syncthreads();

  unsigned c0 = hist[tid*4], c1 = hist[tid*4+1], c2 = hist[tid*4+2], c3 = hist[tid*4+3];
  unsigned st = c0 + c1 + c2 + c3;
  unsigned I = suffix1024v(st, swq, tid);
  unsigned H = I - st;
  if (H < k && k <= I) {          // exactly one thread crosses
    unsigned cum = H;
    if (cum + c3 >= k)      { *sh_sel = tid*4+3; *sh_r = k - cum; }
    else { cum += c3;
      if (cum + c2 >= k)    { *sh_sel = tid*4+2; *sh_r = k - cum; }
      else { cum += c2;
        if (cum + c1 >= k)  { *sh_sel = tid*4+1; *sh_r = k - cum; }
        else { cum += c1;     *sh_sel = tid*4;   *sh_r = k - cum; } } }
  }
  __syncthreads();
  const unsigned pref0 = *sh_sel;
  const unsigned r1    = *sh_r;
  __syncthreads();

  // ---- pass 1: 10-bit hist (bits 19:10) for bucket0; reg-accumulate S above
  hist[tid] = 0u; fsum[tid] = 0.f;
  __syncthreads();
  float s_above = 0.f;
  #pragma unroll
  for (int j = 0; j < NL4; ++j)
    if (!GUARD || tid + j * 1024 < n4) {
      #pragma unroll
      for (int cc = 0; cc < 4; ++cc) {
        unsigned u = (&v[j].x)[cc];
        unsigned d = u >> 20;
        float val = __uint_as_float(u & 0x7fffffffu);
        if (d > pref0) s_above += val;
        else if (d == pref0) {
          unsigned s2 = (u >> 10) & 1023u;
          atomicAdd(&hist[s2], 1u);
          atomicAdd(&fsum[s2], val);
        }
      }
    }
  __syncthreads();
  float S0 = blockredf(s_above, swred, tid);

  unsigned cc1 = hist[tid];
  unsigned I1 = suffix1024v(cc1, swq, tid);
  unsigned H1 = I1 - cc1;
  if (H1 < r1 && r1 <= I1) { *sh_sel = (unsigned)tid; *sh_r = r1 - H1; }
  __syncthreads();
  const unsigned sel1 = *sh_sel;
  const unsigned r2   = *sh_r;
  float S1 = blockredf(tid > (int)sel1 ? fsum[tid] : 0.f, swred, tid);

  // ---- pass 2: final 10 bits (9:0)
  hist[tid] = 0u; fsum[tid] = 0.f;
  __syncthreads();
  const unsigned pref01 = (pref0 << 10) | sel1;
  #pragma unroll
  for (int j = 0; j < NL4; ++j)
    if (!GUARD || tid + j * 1024 < n4) {
      #pragma unroll
      for (int cc = 0; cc < 4; ++cc) {
        unsigned u = (&v[j].x)[cc];
        if ((u >> 10) == pref01) {
          atomicAdd(&hist[u & 1023u], 1u);
          atomicAdd(&fsum[u & 1023u], __uint_as_float(u & 0x7fffffffu));
        }
      }
    }
  __syncthreads();

  unsigned cc2 = hist[tid];
  unsigned I2 = suffix1024v(cc2, swq, tid);
  unsigned H2 = I2 - cc2;
  if (H2 < r2 && r2 <= I2) { *sh_sel = (unsigned)tid; *sh_r = r2 - H2; }
  __syncthreads();
  const unsigned sel2 = *sh_sel;
  const unsigned r3   = *sh_r;
  float S2 = blockredf(tid > (int)sel2 ? fsum[tid] : 0.f, swred, tid);

  const unsigned T = (pref01 << 10) | sel2;    // exact k-th largest key
  const float Tval = __uint_as_float(T & 0x7fffffffu);
  return S0 + S1 + S2 + Tval * (float)r3;      // valid on tid 0
}

__global__ __launch_bounds__(1024) void kB(const unsigned* __restrict__ keys,
                                           const float* __restrict__ partials,
                                           float* __restrict__ finals)
{
  __shared__ unsigned hist[4096];
  __shared__ float    fsum[1024];
  __shared__ unsigned swq[16];
  __shared__ float    swred[16];
  __shared__ float    gp[5];
  __shared__ unsigned sh_sel, sh_r;

  const int bl = blockIdx.x, lvl = bl / NB, b = bl % NB, tid = threadIdx.x;
  const int NLs[3]   = {N0, N1, N2};
  const int BASEs[3] = {0, NB * N0, NB * (N0 + N1)};
  const int NSL[3]   = {64, 16, 4};
  const int POFF[3]  = {0, NB * 64 * 5, NB * 64 * 5 + NB * 16 * 5};

  if (tid < 64) {
    float v0=0,v1=0,v2=0,v3=0,v4=0;
    if (tid < NSL[lvl]) {
      const float* pp = partials + POFF[lvl] + (size_t)(b * NSL[lvl] + tid) * 5;
      v0=pp[0]; v1=pp[1]; v2=pp[2]; v3=pp[3]; v4=pp[4];
    }
    v0=wredf(v0); v1=wredf(v1); v2=wredf(v2); v3=wredf(v3); v4=wredf(v4);
    if (tid==0){gp[0]=v0;gp[1]=v1;gp[2]=v2;gp[3]=v3;gp[4]=v4;}
  }
  __syncthreads();
  const int np = (int)gp[3], nn = (int)gp[4];
  const int k  = (np == 0) ? (nn < 100 ? nn : 100)
                           : (np * 3 < nn ? np * 3 : nn);

  float topk = 0.f;
  if (k > 0) {
    const unsigned* kp = keys + BASEs[lvl] + (size_t)b * NLs[lvl];
    if (lvl == 0)      topk = kb_core<12,false>(kp, 12288, (unsigned)k, hist, fsum, swq, swred, &sh_sel, &sh_r, tid);
    else if (lvl == 1) topk = kb_core<3, false>(kp, 3072,  (unsigned)k, hist, fsum, swq, swred, &sh_sel, &sh_r, tid);
    else               topk = kb_core<1, true >(kp, 768,   (unsigned)k, hist, fsum, swq, swred, &sh_sel, &sh_r, tid);
  }
  if (tid == 0) {
    float* f = finals + (size_t)bl * 5;
    f[0] = gp[0];
    f[1] = gp[1] + topk;
    f[2] = gp[2];
    f[3] = gp[3];
    f[4] = (float)k;
  }
}

__global__ void kC(const float* __restrict__ finals, float* __restrict__ out)
{
  const int tid = threadIdx.x;  // 128 threads
  float loc = 0.f, obj = 0.f, cls = 0.f, pos = 0.f, sel = 0.f;
  if (tid < 96) {
    const float* f = finals + (size_t)tid * 5;
    loc = f[0]; obj = f[1]; cls = f[2]; pos = f[3]; sel = f[4];
  }
  loc = wredf(loc); obj = wredf(obj); cls = wredf(cls);
  pos = wredf(pos); sel = wredf(sel);
  __shared__ float sf[5][2];
  const int wv = tid >> 6;
  if ((tid & 63) == 0) { sf[0][wv] = loc; sf[1][wv] = obj; sf[2][wv] = cls;
                         sf[3][wv] = pos; sf[4][wv] = sel; }
  __syncthreads();
  if (tid == 0) {
    float L  = sf[0][0] + sf[0][1];
    float O  = sf[1][0] + sf[1][1];
    float Cl = sf[2][0] + sf[2][1];
    float P  = sf[3][0] + sf[3][1];
    float S  = sf[4][0] + sf[4][1];
    float norm  = fmaxf(P + S, 1.f);
    float l_loc = 2.0f * L / norm;
    float l_obj = O / norm;
    float l_cls = Cl / fmaxf(P, 1.f);
    out[0] = l_loc + l_obj + l_cls;
    out[1] = l_loc;
    out[2] = l_obj;
    out[3] = l_cls;
  }
}

extern "C" void kernel_launch(void* const* d_in, const int* in_sizes, int n_in,
                              void* d_out, int out_size, void* d_ws, size_t ws_size,
                              hipStream_t stream) {
  const float* p1     = (const float*)d_in[0];
  const float* p2     = (const float*)d_in[1];
  const float* p3     = (const float*)d_in[2];
  // d_in[3..5] = anchors (recomputed analytically in-kernel; exact in fp32)
  const float* boxes  = (const float*)d_in[6];
  const int*   labels = (const int*)d_in[7];
  float* out = (float*)d_out;

  char* ws = (char*)d_ws;
  float*    partials = (float*)ws;            // 13440 floats
  float*    finals   = (float*)(ws + 53760);  // 480 floats
  unsigned* keys     = (unsigned*)(ws + 57344);

  kA<<<dim3(84, NB), 256, 0, stream>>>(p1, p2, p3, boxes, labels, keys, partials);
  kB<<<96, 1024, 0, stream>>>(keys, partials, finals);
  kC<<<1, 128, 0, stream>>>(finals, out);
}